// Round 1
// 307.273 us; speedup vs baseline: 1.0315x; 1.0315x over previous
//
#include <hip/hip_runtime.h>
#include <hip/hip_bf16.h>

// ModulatedConv2d (StyleGAN2): B=16, Cin=Cout=128, K=3, H=W=128, STYLE=512
// R4: fused transpose — conv_kernel reads x (fp32 NCHW) directly, converts
//     to bf16 and transposes into LDS-resident rows (y-1,y,y+1) once per
//     cin-half; the nhwc pass and its 136 MB HBM round-trip are eliminated.
//     B fragments come straight from the resident rows for all 9 taps.
//     LDS = 3*128*64 bf16 rows (48K) + 16K A-tile/scratch = exactly 64 KB
//     -> 2 blocks/CU. Edge columns x=-1/x=128 via per-lane clamp+select.

typedef __attribute__((ext_vector_type(8))) short short8;
typedef __attribute__((ext_vector_type(4))) float f32x4;

#define CONV_SCALE 0.029462782549439483f /* 1/sqrt(128*9) */
#define LIN_SCALE 0.04419417382415922f   /* 1/sqrt(512) */

__device__ __forceinline__ void async16(unsigned short* lds, const unsigned short* g) {
  __builtin_amdgcn_global_load_lds((const __attribute__((address_space(1))) void*)g,
                                   (__attribute__((address_space(3))) void*)lds, 16, 0, 0);
}

__device__ __forceinline__ unsigned int pack2bf(float a, float b) {
  unsigned short ha = __builtin_bit_cast(unsigned short, __float2bfloat16(a));
  unsigned short hb = __builtin_bit_cast(unsigned short, __float2bfloat16(b));
  return (unsigned int)ha | ((unsigned int)hb << 16);
}

// s[b][cin] = sum_d style[b,d] * mod_w[cin,d] * LIN_SCALE + mod_b[cin]
__global__ void style_kernel(const float* __restrict__ style, const float* __restrict__ mod_w,
                             const float* __restrict__ mod_b, float* __restrict__ s_ws) {
  const int gw = blockIdx.x * 4 + (threadIdx.x >> 6);  // global wave 0..2047
  const int b = gw >> 7, cin = gw & 127, lane = threadIdx.x & 63;
  const float4 s0 = *(const float4*)(style + (size_t)b * 512 + lane * 4);
  const float4 s1 = *(const float4*)(style + (size_t)b * 512 + 256 + lane * 4);
  const float4 w0 = *(const float4*)(mod_w + (size_t)cin * 512 + lane * 4);
  const float4 w1 = *(const float4*)(mod_w + (size_t)cin * 512 + 256 + lane * 4);
  float acc = s0.x * w0.x + s0.y * w0.y + s0.z * w0.z + s0.w * w0.w +
              s1.x * w1.x + s1.y * w1.y + s1.z * w1.z + s1.w * w1.w;
#pragma unroll
  for (int off = 32; off; off >>= 1) acc += __shfl_xor(acc, off);
  if (lane == 0) s_ws[b * 128 + cin] = acc * LIN_SCALE + mod_b[cin];
}

// one block per (b, cout): wmod = CONV_SCALE*weight*s ; demod = rsqrt(sum wmod^2 + 1e-8)
// write bf16 w_ws[b][ky*3+kx][cout][cin]  (cin fastest, for A-tile staging)
__global__ void modw_kernel(const float* __restrict__ weight, const float* __restrict__ s_ws,
                            unsigned short* __restrict__ w_ws) {
  const int bid = blockIdx.x;
  const int b = bid >> 7, cout = bid & 127;
  const int cin = threadIdx.x;
  const float sv = s_ws[b * 128 + cin] * CONV_SCALE;
  const float* wp = weight + ((size_t)cout * 128 + cin) * 9;
  float v[9];
  float ss = 0.f;
#pragma unroll
  for (int j = 0; j < 9; ++j) { v[j] = wp[j] * sv; ss += v[j] * v[j]; }
#pragma unroll
  for (int off = 32; off; off >>= 1) ss += __shfl_down(ss, off);
  __shared__ float red[2];
  if ((threadIdx.x & 63) == 0) red[threadIdx.x >> 6] = ss;
  __syncthreads();
  const float dem = rsqrtf(red[0] + red[1] + 1e-8f);
#pragma unroll
  for (int j = 0; j < 9; ++j) {
    __hip_bfloat16 h = __float2bfloat16(v[j] * dem);
    w_ws[(((size_t)b * 9 + j) * 128 + cout) * 128 + cin] =
        __builtin_bit_cast(unsigned short, h);
  }
}

// one block per (b, y): out[b][0..127][y][0..127] = sum_{ky,kx,cin} w'*x
// 128x128 tile, 4 waves 2x2, each wave 4x4 of 16x16x32 bf16 MFMA.
// Per cin-half (64): transpose rows y-1,y,y+1 fp32->bf16 into xr, then
// 9 taps: stage A (async16) + MFMA reading B from resident xr.
__global__ __launch_bounds__(256, 2) void conv_kernel(const float* __restrict__ x,
                                                      const unsigned short* __restrict__ wws,
                                                      float* __restrict__ out) {
  __shared__ unsigned short xr[3 * 128 * 64];  // 48 KB: [ky][x 0..127][64 cin], 16B groups XOR (x&7)
  __shared__ unsigned short lA[128 * 64];      // 16 KB: A tile; doubles as transpose scratch

  const int tid = threadIdx.x;
  // XCD-aware swizzle: XCD x gets contiguous (b,y) range so adjacent-y row reuse hits its L2.
  const int bid = (blockIdx.x & 7) * 256 + (blockIdx.x >> 3);
  const int b = bid >> 7, y = bid & 127;
  const int lane = tid & 63, w = tid >> 6;
  const int wm = w & 1, wn = w >> 1;
  const int l15 = lane & 15, q = lane >> 4;

  f32x4 acc[4][4];
#pragma unroll
  for (int i = 0; i < 4; ++i)
#pragma unroll
    for (int t = 0; t < 4; ++t) acc[i][t] = (f32x4){0.f, 0.f, 0.f, 0.f};

  const float* xb = x + (size_t)b * (128 * 16384);
  const unsigned short* wb = wws + (size_t)b * 9 * 128 * 128;

  // A staging addresses (pre-swizzled global source, linear LDS dest)
  const int mbase = tid >> 3;
  const int goff = (((tid & 7) ^ ((tid >> 3) & 7)) << 3);
  const int eoff = tid * 8;

  // transpose thread mapping
  const int xq = tid & 31, cq8 = tid >> 5;   // load: x-quad, cin-quad-of-8
  const int tg16 = tid & 7, txr = tid >> 3;  // readback: 16B cin group, x row

  // B pixel columns per t (loop-invariant)
  int nt[4];
#pragma unroll
  for (int t = 0; t < 4; ++t) nt[t] = wn * 64 + t * 16 + l15;

  const short8 zero8 = {0, 0, 0, 0, 0, 0, 0, 0};

  for (int c0 = 0; c0 < 128; c0 += 64) {
    // ---- T phase: transpose 3 input rows (this cin-half) into xr ----
#pragma unroll
    for (int r3 = 0; r3 < 3; ++r3) {
      const int yy = y + r3 - 1;
      if (yy < 0 || yy > 127) continue;  // uniform per block
      __syncthreads();                   // lA free (prev MFMA / prev scratch reads done)
      const float* xrow = xb + (size_t)c0 * 16384 + (size_t)yy * 128;
      float4 f[2][4];
#pragma unroll
      for (int rr = 0; rr < 2; ++rr)
#pragma unroll
        for (int j = 0; j < 4; ++j)
          f[rr][j] = *(const float4*)(xrow + (size_t)(rr * 32 + cq8 * 4 + j) * 16384 + xq * 4);
      // in-register 4x4 transpose -> 8B swizzled scratch (gp = g8 ^ (x&15))
#pragma unroll
      for (int rr = 0; rr < 2; ++rr) {
        const int g8 = rr * 8 + cq8;  // cin_local/4
#pragma unroll
        for (int i = 0; i < 4; ++i) {
          const int xp = xq * 4 + i;
          const int gp = g8 ^ (xp & 15);
          uint2 col;
          col.x = pack2bf(((const float*)&f[rr][0])[i], ((const float*)&f[rr][1])[i]);
          col.y = pack2bf(((const float*)&f[rr][2])[i], ((const float*)&f[rr][3])[i]);
          *(uint2*)(lA + xp * 64 + gp * 4) = col;
        }
      }
      __syncthreads();
      // scratch -> xr with the MFMA-read swizzle (16B groups XOR (x&7))
#pragma unroll
      for (int rr = 0; rr < 4; ++rr) {
        const int xp = rr * 32 + txr;
        const int s15 = xp & 15;
        const int gp0 = (tg16 * 2) ^ s15, gp1 = (tg16 * 2 + 1) ^ s15;
        const uint2 a = *(const uint2*)(lA + xp * 64 + gp0 * 4);
        const uint2 c = *(const uint2*)(lA + xp * 64 + gp1 * 4);
        uint4 o;
        o.x = a.x; o.y = a.y; o.z = c.x; o.w = c.y;
        *(uint4*)(xr + r3 * 8192 + xp * 64 + ((tg16 ^ (xp & 7)) << 3)) = o;
      }
    }

    // ---- K phase: 9 taps, stage A only, B from resident xr ----
    for (int j3 = 0; j3 < 9; ++j3) {
      const int ky = j3 / 3, kx = j3 - ky * 3;
      const int yy = y + ky - 1;
      if (yy < 0 || yy > 127) continue;  // uniform per block
      __syncthreads();                   // lA free (prev MFMA reads / scratch done)
#pragma unroll
      for (int p = 0; p < 4; ++p)
        async16(lA + p * 2048 + eoff, wb + j3 * 16384 + c0 + p * 4096 + mbase * 128 + goff);
      // B columns for this tap: x = n + kx - 1, clamp+select at the 2 edges
      int xcb[4];
#pragma unroll
      for (int t = 0; t < 4; ++t) xcb[t] = nt[t] + (kx - 1);
      const bool lo = (xcb[0] < 0);    // only kx==0, wn==0, l15==0 lanes
      const bool hi = (xcb[3] > 127);  // only kx==2, wn==1, l15==15 lanes
      if (lo) xcb[0] = 0;
      if (hi) xcb[3] = 127;
      const unsigned short* xkr = xr + ky * 8192;
      __syncthreads();
#pragma unroll
      for (int s = 0; s < 2; ++s) {
        const int s4q = s * 4 + q;
        const int axor = ((s4q ^ (l15 & 7)) << 3);
        short8 af[4], bf[4];
#pragma unroll
        for (int i = 0; i < 4; ++i)
          af[i] = *(const short8*)(lA + (wm * 64 + i * 16 + l15) * 64 + axor);
#pragma unroll
        for (int t = 0; t < 4; ++t)
          bf[t] = *(const short8*)(xkr + xcb[t] * 64 + ((s4q ^ (xcb[t] & 7)) << 3));
        if (lo) bf[0] = zero8;
        if (hi) bf[3] = zero8;
#pragma unroll
        for (int i = 0; i < 4; ++i)
#pragma unroll
          for (int t = 0; t < 4; ++t)
            acc[i][t] = __builtin_amdgcn_mfma_f32_16x16x32_bf16(af[i], bf[t], acc[i][t], 0, 0, 0);
      }
    }
  }

  // C/D layout: col(pixel) = lane&15, row(cout) = (lane>>4)*4 + reg
  float* ob = out + ((size_t)b * 128 * 128 + y) * 128;
#pragma unroll
  for (int i = 0; i < 4; ++i) {
    const int coutb = wm * 64 + i * 16 + q * 4;
#pragma unroll
    for (int r = 0; r < 4; ++r) {
      float* orow = ob + (size_t)(coutb + r) * (128 * 128);
#pragma unroll
      for (int t = 0; t < 4; ++t) orow[wn * 64 + t * 16 + l15] = acc[i][t][r];
    }
  }
}

extern "C" void kernel_launch(void* const* d_in, const int* in_sizes, int n_in,
                              void* d_out, int out_size, void* d_ws, size_t ws_size,
                              hipStream_t stream) {
  const float* x = (const float*)d_in[0];
  const float* style = (const float*)d_in[1];
  const float* weight = (const float*)d_in[2];
  const float* mod_w = (const float*)d_in[3];
  const float* mod_b = (const float*)d_in[4];
  float* out = (float*)d_out;

  char* ws = (char*)d_ws;
  float* s_ws = (float*)ws;                             // 8 KB
  unsigned short* w_ws = (unsigned short*)(ws + 8192);  // 4.7 MB

  style_kernel<<<512, 256, 0, stream>>>(style, mod_w, mod_b, s_ws);
  modw_kernel<<<16 * 128, 128, 0, stream>>>(weight, s_ws, w_ws);
  conv_kernel<<<16 * 128, 256, 0, stream>>>(x, w_ws, out);
}